// Round 7
// baseline (113.378 us; speedup 1.0000x reference)
//
#include <hip/hip_runtime.h>

#define N      384
#define BSZ    192
#define NM1    383
#define D      1024
#define DELTA  0.1f
#define NT     24                    // 16-row tiles per dim
#define NTILES (NT * (NT + 1) / 2)   // 300 upper-tri tiles
#define GRID   N                     // 384 blocks, all co-resident (>=2/CU)

typedef __attribute__((ext_vector_type(8))) short bf16x8;
typedef __attribute__((ext_vector_type(4))) float f32x4;

__device__ __forceinline__ const float* feat_row(const float* feats, int i) {
    // features laid out [192][2][1024]; logical row i of the [384,1024] concat
    int b = (i < BSZ) ? i : (i - BSZ);
    int s = (i < BSZ) ? 0 : 1;
    return feats + (size_t)(b * 2 + s) * D;
}

__device__ __forceinline__ unsigned short f2bf(float x) {  // RNE f32->bf16
    unsigned u = __builtin_bit_cast(unsigned, x);
    u = (u + 0x7FFFu + ((u >> 16) & 1u)) >> 16;
    return (unsigned short)u;
}
__device__ __forceinline__ float bf2f(unsigned short h) {
    unsigned u = ((unsigned)h) << 16;
    return __builtin_bit_cast(float, u);
}

// Grid-wide rendezvous: all blocks co-resident (launch_bounds guarantees
// 2 blocks/CU min occupancy; 384 <= 512). Release: syncthreads has drained
// each wave's stores (vmcnt), threadfence does agent-scope wb; acquire:
// threadfence after spin invalidates L1/L2 before any consumer load.
__device__ __forceinline__ void grid_barrier(unsigned* c, unsigned tgt) {
    __syncthreads();
    if (threadIdx.x == 0) {
        __threadfence();
        atomicAdd(c, 1u);
        while (__hip_atomic_load(c, __ATOMIC_RELAXED, __HIP_MEMORY_SCOPE_AGENT) < tgt)
            __builtin_amdgcn_s_sleep(1);
        __threadfence();
    }
    __syncthreads();
}

__global__ __launch_bounds__(256, 2)
void k_mega(const float* __restrict__ feats, const int* __restrict__ labels,
            unsigned short* Hb, unsigned short* Lb, float* sq, float* z,
            float* partial, unsigned* ctr, float* out) {
    const int b = blockIdx.x, tid = threadIdx.x;
    const int lane = tid & 63, wv = tid >> 6;

    __shared__ float redf[4];
    __shared__ f32x4 red[4][64];
    // phase C state
    __shared__ float zbuf[NM1];
    __shared__ unsigned char yrow[NM1];
    __shared__ int cnt[64], startv[64], cur[64];
    __shared__ float rankd[64];
    __shared__ float2 zr[N];
    __shared__ unsigned grs[N];
    __shared__ int lastFlag;
    __shared__ double dp[4];

    // ---------- phase A: bf16 split (H+L) + |f|^2 for row b ----------
    {
        const float4 v = ((const float4*)feat_row(feats, b))[tid];  // 256*4 = 1024
        float p = 0.f;
        p = fmaf(v.x, v.x, p); p = fmaf(v.y, v.y, p);
        p = fmaf(v.z, v.z, p); p = fmaf(v.w, v.w, p);
        ushort4 h, l;
        h.x = f2bf(v.x); l.x = f2bf(v.x - bf2f(h.x));
        h.y = f2bf(v.y); l.y = f2bf(v.y - bf2f(h.y));
        h.z = f2bf(v.z); l.z = f2bf(v.z - bf2f(h.z));
        h.w = f2bf(v.w); l.w = f2bf(v.w - bf2f(h.w));
        *(ushort4*)(Hb + (size_t)b * D + tid * 4) = h;
        *(ushort4*)(Lb + (size_t)b * D + tid * 4) = l;
#pragma unroll
        for (int off = 32; off; off >>= 1) p += __shfl_xor(p, off);
        if (lane == 0) redf[wv] = p;
        __syncthreads();
        if (tid == 0) sq[b] = redf[0] + redf[1] + redf[2] + redf[3];
    }
    grid_barrier(&ctr[0], GRID);

    // ---------- phase B: Gram tile via MFMA (blocks 0..299) ----------
    // G = H*H^T + H*L^T + L*H^T (LL^T dropped, ~1e-4). 16x16 tile per block,
    // 4 waves split K=1024; 3 independent MFMA accumulator chains.
    if (b < NTILES) {
        int t = b, bi = 0;
        while (t >= NT - bi) { t -= NT - bi; ++bi; }
        const int bj = bi + t;
        const int i0 = bi * 16, j0 = bj * 16;
        const bool diag = (bi == bj);

        const size_t arow = (size_t)(i0 + (lane & 15)) * D + wv * 256 + (lane >> 4) * 8;
        const size_t brow = (size_t)(j0 + (lane & 15)) * D + wv * 256 + (lane >> 4) * 8;

        f32x4 aHH = {0.f,0.f,0.f,0.f}, aHL = {0.f,0.f,0.f,0.f}, aLH = {0.f,0.f,0.f,0.f};
#pragma unroll
        for (int s = 0; s < 8; ++s) {
            bf16x8 aH = *(const bf16x8*)(Hb + arow + s * 32);
            bf16x8 aL = *(const bf16x8*)(Lb + arow + s * 32);
            bf16x8 bH = *(const bf16x8*)(Hb + brow + s * 32);
            bf16x8 bL = *(const bf16x8*)(Lb + brow + s * 32);
            aHH = __builtin_amdgcn_mfma_f32_16x16x32_bf16(aH, bH, aHH, 0, 0, 0);
            aHL = __builtin_amdgcn_mfma_f32_16x16x32_bf16(aH, bL, aHL, 0, 0, 0);
            aLH = __builtin_amdgcn_mfma_f32_16x16x32_bf16(aL, bH, aLH, 0, 0, 0);
        }
        red[wv][lane] = aHH + aHL + aLH;
        __syncthreads();
        const int ls = tid & 63, r = tid >> 6;
        float g = red[0][ls][r] + red[1][ls][r] + red[2][ls][r] + red[3][ls][r];
        // C/D layout (verified): col = lane&15, row = (lane>>4)*4 + reg
        const int jj = j0 + (ls & 15);
        const int ii = i0 + ((ls >> 4) << 2) + r;
        if (ii != jj && (!diag || ii < jj)) {
            float sd = fmaxf(sq[ii] + sq[jj] - 2.f * g, 0.f);
            float v  = sqrtf(sd);
            z[ii * NM1 + (jj < ii ? jj : jj - 1)] = v;
            z[jj * NM1 + (ii < jj ? ii : ii - 1)] = v;
        }
    }
    grid_barrier(&ctr[1], GRID);

    // ---------- phase C: per-row loss (row b) ----------
    {
        const int i = b;
        if (tid < 64) cnt[tid] = 0;
        for (int k = tid; k < NM1; k += 256) zbuf[k] = z[i * NM1 + k];
        __syncthreads();
        const int li = labels[(i < BSZ) ? i : (i - BSZ)];
        for (int k = tid; k < NM1; k += 256) {
            int col = k + (k >= i ? 1 : 0);
            int ya  = abs(li - labels[(col < BSZ) ? col : (col - BSZ)]);
            yrow[k] = (unsigned char)ya;
            atomicAdd(&cnt[ya], 1);
        }
        __syncthreads();
        if (tid == 0) {
            int c = 0, rr = 0;
            for (int v = 0; v < 64; ++v) {
                startv[v] = c;
                rankd[v]  = (float)rr * DELTA;
                if (cnt[v] > 0) ++rr;
                c += cnt[v];
            }
        }
        __syncthreads();
        if (tid < 64) cur[tid] = startv[tid];
        __syncthreads();
        for (int k = tid; k < NM1; k += 256) {
            int ya  = yrow[k];
            int pos = atomicAdd(&cur[ya], 1);
            zr[pos]  = make_float2(zbuf[k], rankd[ya]);
            grs[pos] = (unsigned)startv[ya] | ((unsigned)(startv[ya] + cnt[ya]) << 9);
        }
        if (tid == 0) zr[NM1] = make_float2(0.f, 0.f);
        __syncthreads();

        // all-pairs term: (|zk-zj| - |rk-rj|)^2, 2 k-slots per thread
        const float zk0 = zr[tid].x, rk0 = zr[tid].y;
        const bool  v1  = (tid + 256 < NM1);
        const int   k1  = v1 ? tid + 256 : NM1;
        const float zk1 = zr[k1].x, rk1 = zr[k1].y;

        float s0 = 0.f, s1 = 0.f;
#define PAIRQ(q) do { \
        float t0 = fabsf(zk0 - (q).x) - fabsf(rk0 - (q).y); s0 = fmaf(t0, t0, s0); \
        float t1 = fabsf(zk1 - (q).x) - fabsf(rk1 - (q).y); s1 = fmaf(t1, t1, s1); \
    } while (0)
        int j = 0;
        for (; j + 4 <= NM1; j += 4) {
            float2 q0 = zr[j], q1 = zr[j+1], q2 = zr[j+2], q3 = zr[j+3];
            PAIRQ(q0); PAIRQ(q1); PAIRQ(q2); PAIRQ(q3);
        }
        for (; j < NM1; ++j) { float2 q = zr[j]; PAIRQ(q); }
#undef PAIRQ
        if (!v1) s1 = 0.f;

        // sparse same-y correction: a*sigmoid(a-DELTA) - a^2 over [lo,hi)
        float cs = 0.f;
        for (int jj = tid; jj < NM1; jj += 256) {
            const float    zj = zr[jj].x;
            const unsigned g  = grs[jj];
            const int lo = g & 0x1FF;
            const int hi = (g >> 9) & 0x1FF;
            for (int k = lo; k < hi; ++k) {
                float a = fabsf(zr[k].x - zj);
                cs += a * __builtin_amdgcn_rcpf(1.f + __expf(DELTA - a)) - a * a;
            }
        }

        float sum = s0 + s1 + cs;
#pragma unroll
        for (int off = 32; off; off >>= 1) sum += __shfl_xor(sum, off);
        if ((tid & 63) == 0) redf[tid >> 6] = sum;
        __syncthreads();
        if (tid == 0) {
            partial[i] = redf[0] + redf[1] + redf[2] + redf[3];
            __threadfence();
            unsigned old = atomicAdd(&ctr[2], 1u);
            lastFlag = (old == N - 1);
        }
        __syncthreads();

        if (lastFlag) {
            // atomic reads bypass any stale per-XCD L2 lines
            double s = 0.0;
            for (int t2 = tid; t2 < N; t2 += 256) s += (double)atomicAdd(&partial[t2], 0.f);
#pragma unroll
            for (int off = 32; off; off >>= 1) s += __shfl_xor(s, off);
            if ((tid & 63) == 0) dp[tid >> 6] = s;
            __syncthreads();
            if (tid == 0) {
                const double M = (double)N * (double)NM1 * (double)NM1;
                out[0] = (float)((dp[0] + dp[1] + dp[2] + dp[3]) / M);
            }
        }
    }
}

extern "C" void kernel_launch(void* const* d_in, const int* in_sizes, int n_in,
                              void* d_out, int out_size, void* d_ws, size_t ws_size,
                              hipStream_t stream) {
    const float* feats  = (const float*)d_in[0];
    const int*   labels = (const int*)d_in[1];
    float*       out    = (float*)d_out;

    // ws layout (~2.2 MB total):
    char* ws = (char*)d_ws;
    float*          sq      = (float*)ws;                          // 1536 B
    unsigned*       ctr     = (unsigned*)(ws + 2048);              // 16 B (3 used)
    float*          partial = (float*)(ws + 4096);                 // 1536 B
    unsigned short* Hb      = (unsigned short*)(ws + 16384);       // 768 KiB
    unsigned short* Lb      = (unsigned short*)(ws + 16384 + 786432);        // 768 KiB
    float*          z       = (float*)(ws + 16384 + 2 * 786432);   // 588 KiB

    hipMemsetAsync(ctr, 0, 16, stream);
    k_mega<<<GRID, 256, 0, stream>>>(feats, labels, Hb, Lb, sq, z, partial, ctr, out);
}

// Round 8
// 39.962 us; speedup vs baseline: 2.8372x; 2.8372x over previous
//
#include <hip/hip_runtime.h>

#define N     384
#define BSZ   192
#define NM1   383
#define D     1024
#define DELTA 0.1f
#define NT    24                    // 16-row panels / tiles per dim
#define NTILES (NT * (NT + 1) / 2)  // 300 upper-tri tiles
#define PANEL 16384                 // halfs per panel: 16 rows * 1024

typedef __attribute__((ext_vector_type(8))) short bf16x8;
typedef __attribute__((ext_vector_type(4))) float f32x4;

__device__ __forceinline__ const float* feat_row(const float* feats, int i) {
    // features laid out [192][2][1024]; logical row i of the [384,1024] concat
    int b = (i < BSZ) ? i : (i - BSZ);
    int s = (i < BSZ) ? 0 : 1;
    return feats + (size_t)(b * 2 + s) * D;
}

__device__ __forceinline__ unsigned short f2bf(float x) {  // RNE f32->bf16
    unsigned u = __builtin_bit_cast(unsigned, x);
    u = (u + 0x7FFFu + ((u >> 16) & 1u)) >> 16;
    return (unsigned short)u;
}
__device__ __forceinline__ float bf2f(unsigned short h) {
    unsigned u = ((unsigned)h) << 16;
    return __builtin_bit_cast(float, u);
}

// Fragment-major tiled index: (row, k) -> [row/16][k/8][row%16][k%8]
__device__ __forceinline__ size_t tidx(int row, int k) {
    return (size_t)(row >> 4) * PANEL + (size_t)(k >> 3) * 128
         + (size_t)(row & 15) * 8 + (k & 7);
}

// f32 -> (H, L) bf16 split in fragment-major layout + |f|^2; 4 rows/block.
__global__ __launch_bounds__(256) void k_cvt(const float* __restrict__ feats,
                                             unsigned short* __restrict__ Ht,
                                             unsigned short* __restrict__ Lt,
                                             float* __restrict__ sq,
                                             unsigned* __restrict__ counter) {
    const int lane = threadIdx.x & 63, wv = threadIdx.x >> 6;
    const int i = blockIdx.x * 4 + wv;
    if (blockIdx.x == 0 && threadIdx.x == 0) *counter = 0u;
    const float4* f4 = (const float4*)feat_row(feats, i);
    float p = 0.f;
#pragma unroll
    for (int c = 0; c < 4; ++c) {
        float4 v = f4[lane + 64 * c];
        p = fmaf(v.x, v.x, p); p = fmaf(v.y, v.y, p);
        p = fmaf(v.z, v.z, p); p = fmaf(v.w, v.w, p);
        ushort4 h, l;
        h.x = f2bf(v.x); l.x = f2bf(v.x - bf2f(h.x));
        h.y = f2bf(v.y); l.y = f2bf(v.y - bf2f(h.y));
        h.z = f2bf(v.z); l.z = f2bf(v.z - bf2f(h.z));
        h.w = f2bf(v.w); l.w = f2bf(v.w - bf2f(h.w));
        const int e = 4 * (lane + 64 * c);
        const size_t o = tidx(i, e);       // e%8 in {0,4}: 8B-aligned slot
        *(ushort4*)(Ht + o) = h;
        *(ushort4*)(Lt + o) = l;
    }
#pragma unroll
    for (int off = 32; off; off >>= 1) p += __shfl_xor(p, off);
    if (lane == 0) sq[i] = p;
}

// Gram via MFMA on fragment-major H/L: every fragment load is a contiguous
// 1KB wave segment. 300 upper-tri 16x16 tiles; 4 waves split K (256 each);
// 3 independent MFMA chains; cross-wave LDS reduce; mirrored z writes.
// G = H*H^T + H*L^T + L*H^T (LL^T dropped, ~1e-4 on G).
__global__ __launch_bounds__(256) void k_gram(const unsigned short* __restrict__ Ht,
                                              const unsigned short* __restrict__ Lt,
                                              const float* __restrict__ sq,
                                              float* __restrict__ z) {
    int t = blockIdx.x, bi = 0;
    while (t >= NT - bi) { t -= NT - bi; ++bi; }
    const int bj = bi + t;
    const bool diag = (bi == bj);

    const int tid = threadIdx.x;
    const int lane = tid & 63, wv = tid >> 6;

    // lane's fragment slot: row = lane&15, k8-subgroup = lane>>4; wave's
    // K-quarter starts at k8 = wv*32; s-step advances 4 k8 (=32 k) = 512 halfs.
    const size_t aBase = (size_t)bi * PANEL + (size_t)(wv * 32 + (lane >> 4)) * 128
                       + (size_t)(lane & 15) * 8;
    const size_t bBase = (size_t)bj * PANEL + (size_t)(wv * 32 + (lane >> 4)) * 128
                       + (size_t)(lane & 15) * 8;

    f32x4 aHH = {0.f,0.f,0.f,0.f}, aHL = {0.f,0.f,0.f,0.f}, aLH = {0.f,0.f,0.f,0.f};
#pragma unroll
    for (int s = 0; s < 8; ++s) {
        bf16x8 aH = *(const bf16x8*)(Ht + aBase + s * 512);
        bf16x8 aL = *(const bf16x8*)(Lt + aBase + s * 512);
        bf16x8 bH = *(const bf16x8*)(Ht + bBase + s * 512);
        bf16x8 bL = *(const bf16x8*)(Lt + bBase + s * 512);
        aHH = __builtin_amdgcn_mfma_f32_16x16x32_bf16(aH, bH, aHH, 0, 0, 0);
        aHL = __builtin_amdgcn_mfma_f32_16x16x32_bf16(aH, bL, aHL, 0, 0, 0);
        aLH = __builtin_amdgcn_mfma_f32_16x16x32_bf16(aL, bH, aLH, 0, 0, 0);
    }
    __shared__ f32x4 red[4][64];
    red[wv][lane] = aHH + aHL + aLH;
    __syncthreads();
    const int ls = tid & 63, r = tid >> 6;
    float g = red[0][ls][r] + red[1][ls][r] + red[2][ls][r] + red[3][ls][r];
    // C/D layout (verified): col = lane&15, row = (lane>>4)*4 + reg
    const int jj = bj * 16 + (ls & 15);
    const int ii = bi * 16 + ((ls >> 4) << 2) + r;
    if (ii != jj && (!diag || ii < jj)) {
        float sd = fmaxf(sq[ii] + sq[jj] - 2.f * g, 0.f);
        float v  = sqrtf(sd);
        z[ii * NM1 + (jj < ii ? jj : jj - 1)] = v;
        z[jj * NM1 + (ii < jj ? ii : ii - 1)] = v;
    }
}

// One block per row: LDS counting sort by y_abs, all-pairs quadratic term,
// sparse same-y correction, per-row partial; last block reduces -> out.
__global__ __launch_bounds__(256) void k_main(const float* __restrict__ z,
                                              const int* __restrict__ labels,
                                              float* __restrict__ partial,
                                              unsigned* __restrict__ counter,
                                              float* __restrict__ out) {
    const int i = blockIdx.x, tid = threadIdx.x;
    __shared__ float zbuf[NM1];
    __shared__ unsigned char yrow[NM1];
    __shared__ int cnt[64], startv[64], cur[64];
    __shared__ float rankd[64];
    __shared__ float2 zr[N];      // sorted (z, rank*DELTA); slot 383 = pad
    __shared__ unsigned grs[N];   // lo | hi<<9 per sorted slot
    __shared__ int lastFlag;

    if (tid < 64) cnt[tid] = 0;
    for (int k = tid; k < NM1; k += 256) zbuf[k] = z[i * NM1 + k];
    __syncthreads();
    const int li = labels[(i < BSZ) ? i : (i - BSZ)];
    for (int k = tid; k < NM1; k += 256) {
        int col = k + (k >= i ? 1 : 0);
        int ya  = abs(li - labels[(col < BSZ) ? col : (col - BSZ)]);
        yrow[k] = (unsigned char)ya;
        atomicAdd(&cnt[ya], 1);
    }
    __syncthreads();
    if (tid == 0) {
        int c = 0, r = 0;
        for (int v = 0; v < 64; ++v) {
            startv[v] = c;
            rankd[v]  = (float)r * DELTA;
            if (cnt[v] > 0) ++r;
            c += cnt[v];
        }
    }
    __syncthreads();
    if (tid < 64) cur[tid] = startv[tid];
    __syncthreads();
    for (int k = tid; k < NM1; k += 256) {
        int ya  = yrow[k];
        int pos = atomicAdd(&cur[ya], 1);
        zr[pos]  = make_float2(zbuf[k], rankd[ya]);
        grs[pos] = (unsigned)startv[ya] | ((unsigned)(startv[ya] + cnt[ya]) << 9);
    }
    if (tid == 0) zr[NM1] = make_float2(0.f, 0.f);
    __syncthreads();

    // all-pairs term: (|zk-zj| - |rk-rj|)^2, 2 k-slots per thread
    const float zk0 = zr[tid].x, rk0 = zr[tid].y;
    const bool  v1  = (tid + 256 < NM1);
    const int   k1  = v1 ? tid + 256 : NM1;   // pad slot; s1 masked below
    const float zk1 = zr[k1].x, rk1 = zr[k1].y;

    float s0 = 0.f, s1 = 0.f;
#define PAIRQ(q) do { \
        float t0 = fabsf(zk0 - (q).x) - fabsf(rk0 - (q).y); s0 = fmaf(t0, t0, s0); \
        float t1 = fabsf(zk1 - (q).x) - fabsf(rk1 - (q).y); s1 = fmaf(t1, t1, s1); \
    } while (0)
    int j = 0;
    for (; j + 4 <= NM1; j += 4) {
        float2 q0 = zr[j], q1 = zr[j+1], q2 = zr[j+2], q3 = zr[j+3];
        PAIRQ(q0); PAIRQ(q1); PAIRQ(q2); PAIRQ(q3);
    }
    for (; j < NM1; ++j) { float2 q = zr[j]; PAIRQ(q); }
#undef PAIRQ
    if (!v1) s1 = 0.f;

    // correction over same-y pairs: a*sigmoid(a-DELTA) - a^2 over [lo,hi)
    float cs = 0.f;
    for (int jj = tid; jj < NM1; jj += 256) {
        const float    zj = zr[jj].x;
        const unsigned g  = grs[jj];
        const int lo = g & 0x1FF;
        const int hi = (g >> 9) & 0x1FF;
        for (int k = lo; k < hi; ++k) {
            float a = fabsf(zr[k].x - zj);
            cs += a * __builtin_amdgcn_rcpf(1.f + __expf(DELTA - a)) - a * a;
        }
    }

    float sum = s0 + s1 + cs;
#pragma unroll
    for (int off = 32; off; off >>= 1) sum += __shfl_xor(sum, off);
    __shared__ float part[4];
    if ((tid & 63) == 0) part[tid >> 6] = sum;
    __syncthreads();
    if (tid == 0) {
        partial[i] = part[0] + part[1] + part[2] + part[3];
        __threadfence();
        unsigned old = atomicAdd(counter, 1u);
        lastFlag = (old == N - 1);
    }
    __syncthreads();

    if (lastFlag) {
        // atomic reads bypass any stale per-XCD L2 lines
        double s = 0.0;
        for (int t2 = tid; t2 < N; t2 += 256) s += (double)atomicAdd(&partial[t2], 0.f);
#pragma unroll
        for (int off = 32; off; off >>= 1) s += __shfl_xor(s, off);
        __shared__ double dp[4];
        if ((tid & 63) == 0) dp[tid >> 6] = s;
        __syncthreads();
        if (tid == 0) {
            const double M = (double)N * (double)NM1 * (double)NM1;
            out[0] = (float)((dp[0] + dp[1] + dp[2] + dp[3]) / M);
        }
    }
}

extern "C" void kernel_launch(void* const* d_in, const int* in_sizes, int n_in,
                              void* d_out, int out_size, void* d_ws, size_t ws_size,
                              hipStream_t stream) {
    const float* feats  = (const float*)d_in[0];
    const int*   labels = (const int*)d_in[1];
    float*       out    = (float*)d_out;

    // ws layout (~2.2 MB total):
    char* ws = (char*)d_ws;
    float*          sq      = (float*)ws;                          // 1536 B
    unsigned*       counter = (unsigned*)(ws + 2048);              // 4 B
    float*          partial = (float*)(ws + 4096);                 // 1536 B
    unsigned short* Ht      = (unsigned short*)(ws + 16384);       // 768 KiB
    unsigned short* Lt      = (unsigned short*)(ws + 16384 + 786432);        // 768 KiB
    float*          z       = (float*)(ws + 16384 + 2 * 786432);   // 588 KiB

    k_cvt <<<N / 4, 256, 0, stream>>>(feats, Ht, Lt, sq, counter);
    k_gram<<<NTILES, 256, 0, stream>>>(Ht, Lt, sq, z);
    k_main<<<N, 256, 0, stream>>>(z, labels, partial, counter, out);
}

// Round 9
// 33.536 us; speedup vs baseline: 3.3808x; 1.1916x over previous
//
#include <hip/hip_runtime.h>

#define N     384
#define BSZ   192
#define NM1   383
#define D     1024
#define DELTA 0.1f
#define NT    24                    // 16-row panels / tiles per dim
#define NTILES (NT * (NT + 1) / 2)  // 300 upper-tri tiles
#define PANEL 16384                 // halfs per panel: 16 rows * 1024

typedef __attribute__((ext_vector_type(8))) short bf16x8;
typedef __attribute__((ext_vector_type(4))) float f32x4;

__device__ __forceinline__ const float* feat_row(const float* feats, int i) {
    // features laid out [192][2][1024]; logical row i of the [384,1024] concat
    int b = (i < BSZ) ? i : (i - BSZ);
    int s = (i < BSZ) ? 0 : 1;
    return feats + (size_t)(b * 2 + s) * D;
}

__device__ __forceinline__ unsigned short f2bf(float x) {  // RNE f32->bf16
    unsigned u = __builtin_bit_cast(unsigned, x);
    u = (u + 0x7FFFu + ((u >> 16) & 1u)) >> 16;
    return (unsigned short)u;
}
__device__ __forceinline__ float bf2f(unsigned short h) {
    unsigned u = ((unsigned)h) << 16;
    return __builtin_bit_cast(float, u);
}

// Fragment-major tiled index: (row, k) -> [row/16][k/8][row%16][k%8]
__device__ __forceinline__ size_t tidx(int row, int k) {
    return (size_t)(row >> 4) * PANEL + (size_t)(k >> 3) * 128
         + (size_t)(row & 15) * 8 + (k & 7);
}

// f32 -> (H, L) bf16 split in fragment-major layout + |f|^2; 4 rows/block.
__global__ __launch_bounds__(256) void k_cvt(const float* __restrict__ feats,
                                             unsigned short* __restrict__ Ht,
                                             unsigned short* __restrict__ Lt,
                                             float* __restrict__ sq,
                                             unsigned* __restrict__ counter) {
    const int lane = threadIdx.x & 63, wv = threadIdx.x >> 6;
    const int i = blockIdx.x * 4 + wv;
    if (blockIdx.x == 0 && threadIdx.x == 0) *counter = 0u;
    const float4* f4 = (const float4*)feat_row(feats, i);
    float p = 0.f;
#pragma unroll
    for (int c = 0; c < 4; ++c) {
        float4 v = f4[lane + 64 * c];
        p = fmaf(v.x, v.x, p); p = fmaf(v.y, v.y, p);
        p = fmaf(v.z, v.z, p); p = fmaf(v.w, v.w, p);
        ushort4 h, l;
        h.x = f2bf(v.x); l.x = f2bf(v.x - bf2f(h.x));
        h.y = f2bf(v.y); l.y = f2bf(v.y - bf2f(h.y));
        h.z = f2bf(v.z); l.z = f2bf(v.z - bf2f(h.z));
        h.w = f2bf(v.w); l.w = f2bf(v.w - bf2f(h.w));
        const int e = 4 * (lane + 64 * c);
        const size_t o = tidx(i, e);       // e%8 in {0,4}: 8B-aligned slot
        *(ushort4*)(Ht + o) = h;
        *(ushort4*)(Lt + o) = l;
    }
#pragma unroll
    for (int off = 32; off; off >>= 1) p += __shfl_xor(p, off);
    if (lane == 0) sq[i] = p;
}

// Gram via MFMA on fragment-major H/L: every fragment load is a contiguous
// 1KB wave segment. 300 upper-tri 16x16 tiles; 4 waves split K (256 each);
// 3 independent MFMA chains; cross-wave LDS reduce; mirrored z writes.
// G = H*H^T + H*L^T + L*H^T (LL^T dropped, ~1e-4 on G).
__global__ __launch_bounds__(256) void k_gram(const unsigned short* __restrict__ Ht,
                                              const unsigned short* __restrict__ Lt,
                                              const float* __restrict__ sq,
                                              float* __restrict__ z) {
    int t = blockIdx.x, bi = 0;
    while (t >= NT - bi) { t -= NT - bi; ++bi; }
    const int bj = bi + t;
    const bool diag = (bi == bj);

    const int tid = threadIdx.x;
    const int lane = tid & 63, wv = tid >> 6;

    const size_t aBase = (size_t)bi * PANEL + (size_t)(wv * 32 + (lane >> 4)) * 128
                       + (size_t)(lane & 15) * 8;
    const size_t bBase = (size_t)bj * PANEL + (size_t)(wv * 32 + (lane >> 4)) * 128
                       + (size_t)(lane & 15) * 8;

    f32x4 aHH = {0.f,0.f,0.f,0.f}, aHL = {0.f,0.f,0.f,0.f}, aLH = {0.f,0.f,0.f,0.f};
#pragma unroll
    for (int s = 0; s < 8; ++s) {
        bf16x8 aH = *(const bf16x8*)(Ht + aBase + s * 512);
        bf16x8 aL = *(const bf16x8*)(Lt + aBase + s * 512);
        bf16x8 bH = *(const bf16x8*)(Ht + bBase + s * 512);
        bf16x8 bL = *(const bf16x8*)(Lt + bBase + s * 512);
        aHH = __builtin_amdgcn_mfma_f32_16x16x32_bf16(aH, bH, aHH, 0, 0, 0);
        aHL = __builtin_amdgcn_mfma_f32_16x16x32_bf16(aH, bL, aHL, 0, 0, 0);
        aLH = __builtin_amdgcn_mfma_f32_16x16x32_bf16(aL, bH, aLH, 0, 0, 0);
    }
    __shared__ f32x4 red[4][64];
    red[wv][lane] = aHH + aHL + aLH;
    __syncthreads();
    const int ls = tid & 63, r = tid >> 6;
    float g = red[0][ls][r] + red[1][ls][r] + red[2][ls][r] + red[3][ls][r];
    // C/D layout (verified): col = lane&15, row = (lane>>4)*4 + reg
    const int jj = bj * 16 + (ls & 15);
    const int ii = bi * 16 + ((ls >> 4) << 2) + r;
    if (ii != jj && (!diag || ii < jj)) {
        float sd = fmaxf(sq[ii] + sq[jj] - 2.f * g, 0.f);
        float v  = sqrtf(sd);
        z[ii * NM1 + (jj < ii ? jj : jj - 1)] = v;
        z[jj * NM1 + (ii < jj ? ii : ii - 1)] = v;
    }
}

// One block per row, 512 threads (8 waves -> ~3 waves/SIMD): LDS counting
// sort by y_abs, all-pairs quadratic term (1 k-slot/thread), sparse same-y
// correction, per-row partial; last block reduces -> out.
__global__ __launch_bounds__(512) void k_main(const float* __restrict__ z,
                                              const int* __restrict__ labels,
                                              float* __restrict__ partial,
                                              unsigned* __restrict__ counter,
                                              float* __restrict__ out) {
    const int i = blockIdx.x, tid = threadIdx.x;
    __shared__ float zbuf[NM1];
    __shared__ unsigned char yrow[NM1];
    __shared__ int cnt[64], startv[64], cur[64];
    __shared__ float rankd[64];
    __shared__ float2 zr[N];      // sorted (z, rank*DELTA); slot 383 = pad
    __shared__ unsigned grs[N];   // lo | hi<<9 per sorted slot
    __shared__ int lastFlag;

    if (tid < 64) cnt[tid] = 0;
    for (int k = tid; k < NM1; k += 512) zbuf[k] = z[i * NM1 + k];
    __syncthreads();
    const int li = labels[(i < BSZ) ? i : (i - BSZ)];
    for (int k = tid; k < NM1; k += 512) {
        int col = k + (k >= i ? 1 : 0);
        int ya  = abs(li - labels[(col < BSZ) ? col : (col - BSZ)]);
        yrow[k] = (unsigned char)ya;
        atomicAdd(&cnt[ya], 1);
    }
    __syncthreads();
    if (tid == 0) {
        int c = 0, r = 0;
        for (int v = 0; v < 64; ++v) {
            startv[v] = c;
            rankd[v]  = (float)r * DELTA;
            if (cnt[v] > 0) ++r;
            c += cnt[v];
        }
    }
    __syncthreads();
    if (tid < 64) cur[tid] = startv[tid];
    __syncthreads();
    for (int k = tid; k < NM1; k += 512) {
        int ya  = yrow[k];
        int pos = atomicAdd(&cur[ya], 1);
        zr[pos]  = make_float2(zbuf[k], rankd[ya]);
        grs[pos] = (unsigned)startv[ya] | ((unsigned)(startv[ya] + cnt[ya]) << 9);
    }
    if (tid == 0) zr[NM1] = make_float2(0.f, 0.f);
    __syncthreads();

    // all-pairs term: (|zk-zj| - |rk-rj|)^2, one k-slot per thread
    const bool  kv  = (tid < NM1);
    const int   k0  = kv ? tid : NM1;      // pad slot for inactive threads
    const float zk0 = zr[k0].x, rk0 = zr[k0].y;

    float s0 = 0.f;
#define PAIRQ(q) do { \
        float t0 = fabsf(zk0 - (q).x) - fabsf(rk0 - (q).y); s0 = fmaf(t0, t0, s0); \
    } while (0)
    int j = 0;
    for (; j + 8 <= NM1; j += 8) {
        float2 q0 = zr[j],   q1 = zr[j+1], q2 = zr[j+2], q3 = zr[j+3];
        float2 q4 = zr[j+4], q5 = zr[j+5], q6 = zr[j+6], q7 = zr[j+7];
        PAIRQ(q0); PAIRQ(q1); PAIRQ(q2); PAIRQ(q3);
        PAIRQ(q4); PAIRQ(q5); PAIRQ(q6); PAIRQ(q7);
    }
    for (; j < NM1; ++j) { float2 q = zr[j]; PAIRQ(q); }
#undef PAIRQ
    if (!kv) s0 = 0.f;

    // correction over same-y pairs: a*sigmoid(a-DELTA) - a^2 over [lo,hi)
    float cs = 0.f;
    if (kv) {
        const float    zj = zr[tid].x;
        const unsigned g  = grs[tid];
        const int lo = g & 0x1FF;
        const int hi = (g >> 9) & 0x1FF;
        for (int k = lo; k < hi; ++k) {
            float a = fabsf(zr[k].x - zj);
            cs += a * __builtin_amdgcn_rcpf(1.f + __expf(DELTA - a)) - a * a;
        }
    }

    float sum = s0 + cs;
#pragma unroll
    for (int off = 32; off; off >>= 1) sum += __shfl_xor(sum, off);
    __shared__ float part[8];
    if ((tid & 63) == 0) part[tid >> 6] = sum;
    __syncthreads();
    if (tid == 0) {
        float ps = 0.f;
#pragma unroll
        for (int w = 0; w < 8; ++w) ps += part[w];
        partial[i] = ps;
        __threadfence();
        unsigned old = atomicAdd(counter, 1u);
        lastFlag = (old == N - 1);
    }
    __syncthreads();

    if (lastFlag) {
        // atomic reads bypass any stale per-XCD L2 lines
        double s = 0.0;
        for (int t2 = tid; t2 < N; t2 += 512) s += (double)atomicAdd(&partial[t2], 0.f);
#pragma unroll
        for (int off = 32; off; off >>= 1) s += __shfl_xor(s, off);
        __shared__ double dp[8];
        if ((tid & 63) == 0) dp[tid >> 6] = s;
        __syncthreads();
        if (tid == 0) {
            double ds = 0.0;
#pragma unroll
            for (int w = 0; w < 8; ++w) ds += dp[w];
            const double M = (double)N * (double)NM1 * (double)NM1;
            out[0] = (float)(ds / M);
        }
    }
}

extern "C" void kernel_launch(void* const* d_in, const int* in_sizes, int n_in,
                              void* d_out, int out_size, void* d_ws, size_t ws_size,
                              hipStream_t stream) {
    const float* feats  = (const float*)d_in[0];
    const int*   labels = (const int*)d_in[1];
    float*       out    = (float*)d_out;

    // ws layout (~2.2 MB total):
    char* ws = (char*)d_ws;
    float*          sq      = (float*)ws;                          // 1536 B
    unsigned*       counter = (unsigned*)(ws + 2048);              // 4 B
    float*          partial = (float*)(ws + 4096);                 // 1536 B
    unsigned short* Ht      = (unsigned short*)(ws + 16384);       // 768 KiB
    unsigned short* Lt      = (unsigned short*)(ws + 16384 + 786432);        // 768 KiB
    float*          z       = (float*)(ws + 16384 + 2 * 786432);   // 588 KiB

    k_cvt <<<N / 4, 256, 0, stream>>>(feats, Ht, Lt, sq, counter);
    k_gram<<<NTILES, 256, 0, stream>>>(Ht, Lt, sq, z);
    k_main<<<N, 512, 0, stream>>>(z, labels, partial, counter, out);
}